// Round 2
// baseline (1440.087 us; speedup 1.0000x reference)
//
#include <hip/hip_runtime.h>
#include <cstdint>

using u32 = unsigned int;
using u64 = unsigned long long;

#define WDIM 512
#define HDIM 512
#define CHANNELS 80   // 8 batches * 10 classes
#define NBINS 8192
#define CAP 4096
#define TOPK 100
#define NEG_SENTINEL -1e30f

// ---- workspace layout (bytes) ----
#define OFF_HIST   0
#define OFF_CNT    2621440
#define OFF_THRESH 2621760
#define OFF_CV     2622080
#define OFF_CI     3932800
#define OFF_S1S    5243520
#define OFF_S1I    5275520
#define ZERO_BYTES 2621760   // hist + cnt must be zeroed every call

__device__ __forceinline__ float fmax3(float a, float b, float c) {
  return fmaxf(fmaxf(a, b), c);
}

// 10 values of one row: [l, A.x,A.y,A.z,A.w, B.x,B.y,B.z,B.w, r]
struct R10 { float l; float4 A; float4 B; float r; };
// horizontal 3-max for the 8 center positions
struct H8 { float h0, h1, h2, h3, h4, h5, h6, h7; };

__device__ __forceinline__ R10 load_row(const float* __restrict__ chbase, int y,
                                        int x0) {
  R10 o;
  if (y < 0 || y >= HDIM) {
    o.l = NEG_SENTINEL;
    o.A = make_float4(NEG_SENTINEL, NEG_SENTINEL, NEG_SENTINEL, NEG_SENTINEL);
    o.B = o.A;
    o.r = NEG_SENTINEL;
    return o;
  }
  const float* row = chbase + (size_t)y * WDIM;
  o.A = *reinterpret_cast<const float4*>(row + x0);
  o.B = *reinterpret_cast<const float4*>(row + x0 + 4);
  o.l = (x0 > 0) ? row[x0 - 1] : NEG_SENTINEL;
  o.r = (x0 + 8 < WDIM) ? row[x0 + 8] : NEG_SENTINEL;
  return o;
}

__device__ __forceinline__ H8 hmax_row(const R10& t) {
  H8 o;
  o.h0 = fmax3(t.l,   t.A.x, t.A.y);
  o.h1 = fmax3(t.A.x, t.A.y, t.A.z);
  o.h2 = fmax3(t.A.y, t.A.z, t.A.w);
  o.h3 = fmax3(t.A.z, t.A.w, t.B.x);
  o.h4 = fmax3(t.A.w, t.B.x, t.B.y);
  o.h5 = fmax3(t.B.x, t.B.y, t.B.z);
  o.h6 = fmax3(t.B.y, t.B.z, t.B.w);
  o.h7 = fmax3(t.B.z, t.B.w, t.r);
  return o;
}

template <bool COLLECT>
__device__ __forceinline__ void emit(float v, int idx, int ch, int T,
                                     u32* lhist, float* __restrict__ cv,
                                     int* __restrict__ ci, int* __restrict__ cnt) {
  int bin = (int)(__float_as_uint(v) >> 17);
  if constexpr (!COLLECT) {
    atomicAdd(&lhist[bin], 1u);
  } else {
    if (bin >= T) {
      int pos = atomicAdd(&cnt[ch], 1);
      if (pos < CAP) {
        cv[ch * CAP + pos] = v;
        ci[ch * CAP + pos] = idx;
      }
    }
  }
}

// One pass over heat: compute 3x3 NMS survivors.
// COLLECT=false: build per-channel histogram of survivor values (LDS hist).
// COLLECT=true : gather (value,index) of survivors with bin >= thresh[ch].
template <bool COLLECT>
__global__ __launch_bounds__(256) void nms_kernel(
    const float* __restrict__ heat, u32* __restrict__ hist,
    const int* __restrict__ thresh, float* __restrict__ cv,
    int* __restrict__ ci, int* __restrict__ cnt) {
  const int ch = blockIdx.y;
  const float* chbase = heat + (size_t)ch * (WDIM * HDIM);

  __shared__ u32 lhist[COLLECT ? 1 : NBINS];
  if constexpr (!COLLECT) {
    for (int i = threadIdx.x; i < NBINS; i += 256) lhist[i] = 0;
    __syncthreads();
  }
  int T = 0;
  if constexpr (COLLECT) T = thresh[ch];

  const int P = blockIdx.x * 2048 + threadIdx.x * 8;  // 8 px per thread, one row
  const int y = P >> 9;
  const int x0 = P & 511;

  R10 rt = load_row(chbase, y - 1, x0);
  R10 rm = load_row(chbase, y,     x0);
  R10 rb = load_row(chbase, y + 1, x0);
  H8 ht = hmax_row(rt);
  H8 hm = hmax_row(rm);
  H8 hb = hmax_row(rb);

#define DO_PIX(I, VC, HT, HM, HB)                                        \
  {                                                                      \
    float v = (VC);                                                      \
    float mx = fmax3((HT), (HM), (HB));                                  \
    if (v == mx && v > 0.0f)                                             \
      emit<COLLECT>(v, P + (I), ch, T, lhist, cv, ci, cnt);              \
  }
  DO_PIX(0, rm.A.x, ht.h0, hm.h0, hb.h0)
  DO_PIX(1, rm.A.y, ht.h1, hm.h1, hb.h1)
  DO_PIX(2, rm.A.z, ht.h2, hm.h2, hb.h2)
  DO_PIX(3, rm.A.w, ht.h3, hm.h3, hb.h3)
  DO_PIX(4, rm.B.x, ht.h4, hm.h4, hb.h4)
  DO_PIX(5, rm.B.y, ht.h5, hm.h5, hb.h5)
  DO_PIX(6, rm.B.z, ht.h6, hm.h6, hb.h6)
  DO_PIX(7, rm.B.w, ht.h7, hm.h7, hb.h7)
#undef DO_PIX

  if constexpr (!COLLECT) {
    __syncthreads();
    for (int i = threadIdx.x; i < NBINS; i += 256) {
      u32 c = lhist[i];
      if (c) atomicAdd(&hist[ch * NBINS + i], c);
    }
  }
}

// Per-channel: find smallest bin T with suffix_count(T) >= TOPK.
__global__ __launch_bounds__(256) void thresh_kernel(const u32* __restrict__ hist,
                                                     int* __restrict__ thresh) {
  const int ch = blockIdx.x;
  const u32* h = hist + (size_t)ch * NBINS;
  __shared__ u32 csum[256];
  const int t = threadIdx.x;
  u32 s = 0;
#pragma unroll 4
  for (int i = 0; i < NBINS / 256; i++) s += h[t * (NBINS / 256) + i];
  csum[t] = s;
  __syncthreads();
  if (t == 0) {
    u32 cum = 0;
    int c;
    for (c = 255; c >= 0; c--) {
      if (cum + csum[c] >= TOPK) break;
      cum += csum[c];
    }
    int T = 0;
    if (c >= 0) {
      int b;
      for (b = c * (NBINS / 256) + (NBINS / 256) - 1; b >= c * (NBINS / 256); b--) {
        cum += h[b];
        if (cum >= TOPK) break;
      }
      T = b;
    }
    thresh[ch] = T;
  }
}

// key = (float_bits(v) << 32) | ~index : descending sort gives
// (value desc, index asc on ties) == lax.top_k order.
__device__ __forceinline__ void bitonic_desc(u64* keys, int N, int nthr, int tid) {
  for (unsigned size = 2; size <= (unsigned)N; size <<= 1) {
    for (unsigned stride = size >> 1; stride > 0; stride >>= 1) {
      __syncthreads();
      for (unsigned i = tid; i < (unsigned)N; i += nthr) {
        unsigned j = i ^ stride;
        if (j > i) {
          u64 a = keys[i], b = keys[j];
          bool desc = ((i & size) == 0);
          if ((a < b) == desc) { keys[i] = b; keys[j] = a; }
        }
      }
    }
  }
  __syncthreads();
}

// Per-channel exact top-100 of the collected candidates.
__global__ __launch_bounds__(1024) void select_kernel(
    const float* __restrict__ cv, const int* __restrict__ ci,
    const int* __restrict__ cnt, float* __restrict__ s1s, int* __restrict__ s1i) {
  const int ch = blockIdx.x;
  __shared__ u64 keys[CAP];
  const int n = min(cnt[ch], CAP);
  for (int i = threadIdx.x; i < CAP; i += 1024) {
    u64 k = 0;
    if (i < n) {
      u32 vb = __float_as_uint(cv[ch * CAP + i]);
      u32 ib = ~(u32)ci[ch * CAP + i];
      k = ((u64)vb << 32) | ib;
    }
    keys[i] = k;
  }
  bitonic_desc(keys, CAP, 1024, threadIdx.x);
  for (int k = threadIdx.x; k < TOPK; k += 1024) {
    u64 key = keys[k];
    s1s[ch * TOPK + k] = __uint_as_float((u32)(key >> 32));
    s1i[ch * TOPK + k] = (int)(~(u32)key);
  }
}

// Per-batch top-100 over the 10*100 stage-1 candidates; write final outputs.
__global__ __launch_bounds__(256) void batch_topk_kernel(
    const float* __restrict__ s1s, const int* __restrict__ s1i,
    float* __restrict__ out) {
  const int b = blockIdx.x;  // 8 batches
  __shared__ u64 keys[1024];
  for (int i = threadIdx.x; i < 1024; i += 256) {
    u64 k = 0;
    if (i < 1000) {
      u32 vb = __float_as_uint(s1s[b * 1000 + i]);
      k = ((u64)vb << 32) | (u32)(~(u32)i);
    }
    keys[i] = k;
  }
  bitonic_desc(keys, 1024, 256, threadIdx.x);
  for (int k = threadIdx.x; k < TOPK; k += 256) {
    u64 key = keys[k];
    float sc = __uint_as_float((u32)(key >> 32));
    int flat = (int)(~(u32)key);          // c*100 + j
    int cls = flat / 100;
    int spatial = s1i[b * 1000 + flat];   // index within h*w
    out[0 * 800 + b * TOPK + k] = sc;
    out[1 * 800 + b * TOPK + k] = (float)spatial;
    out[2 * 800 + b * TOPK + k] = (float)cls;
    out[3 * 800 + b * TOPK + k] = (float)(spatial >> 9);   // y = idx / 512
    out[4 * 800 + b * TOPK + k] = (float)(spatial & 511);  // x = idx % 512
  }
}

extern "C" void kernel_launch(void* const* d_in, const int* in_sizes, int n_in,
                              void* d_out, int out_size, void* d_ws, size_t ws_size,
                              hipStream_t stream) {
  const float* heat = (const float*)d_in[0];
  char* ws = (char*)d_ws;
  u32*   hist   = (u32*)  (ws + OFF_HIST);
  int*   cnt    = (int*)  (ws + OFF_CNT);
  int*   thresh = (int*)  (ws + OFF_THRESH);
  float* cv     = (float*)(ws + OFF_CV);
  int*   ci     = (int*)  (ws + OFF_CI);
  float* s1s    = (float*)(ws + OFF_S1S);
  int*   s1i    = (int*)  (ws + OFF_S1I);
  float* out = (float*)d_out;

  hipMemsetAsync(d_ws, 0, ZERO_BYTES, stream);

  dim3 nms_grid(128, CHANNELS);  // 128 blocks * 2048 px = 512*512 per channel
  nms_kernel<false><<<nms_grid, 256, 0, stream>>>(heat, hist, thresh, cv, ci, cnt);
  thresh_kernel<<<CHANNELS, 256, 0, stream>>>(hist, thresh);
  nms_kernel<true><<<nms_grid, 256, 0, stream>>>(heat, hist, thresh, cv, ci, cnt);
  select_kernel<<<CHANNELS, 1024, 0, stream>>>(cv, ci, cnt, s1s, s1i);
  batch_topk_kernel<<<8, 256, 0, stream>>>(s1s, s1i, out);
}

// Round 3
// 348.575 us; speedup vs baseline: 4.1313x; 4.1313x over previous
//
#include <hip/hip_runtime.h>
#include <cstdint>

using u32 = unsigned int;
using u64 = unsigned long long;

#define WDIM 512
#define HDIM 512
#define CHANNELS 80   // 8 batches * 10 classes
#define NBINS 8192
#define CAP 4096
#define TOPK 100
#define NEG_SENTINEL -1e30f
#define CNT_STRIDE 16  // u32s per channel counter slot (64B line each)

__device__ __forceinline__ float fmax3(float a, float b, float c) {
  return fmaxf(fmaxf(a, b), c);
}

// 10 values of one row: [l, A.x..A.w, B.x..B.w, r]
struct R10 { float l; float4 A; float4 B; float r; };
struct H8 { float h0, h1, h2, h3, h4, h5, h6, h7; };

__device__ __forceinline__ R10 load_row(const float* __restrict__ chbase, int y,
                                        int x0) {
  R10 o;
  if (y < 0 || y >= HDIM) {
    o.l = NEG_SENTINEL;
    o.A = make_float4(NEG_SENTINEL, NEG_SENTINEL, NEG_SENTINEL, NEG_SENTINEL);
    o.B = o.A;
    o.r = NEG_SENTINEL;
    return o;
  }
  const float* row = chbase + (size_t)y * WDIM;
  o.A = *reinterpret_cast<const float4*>(row + x0);
  o.B = *reinterpret_cast<const float4*>(row + x0 + 4);
  o.l = (x0 > 0) ? row[x0 - 1] : NEG_SENTINEL;
  o.r = (x0 + 8 < WDIM) ? row[x0 + 8] : NEG_SENTINEL;
  return o;
}

__device__ __forceinline__ H8 hmax_row(const R10& t) {
  H8 o;
  o.h0 = fmax3(t.l,   t.A.x, t.A.y);
  o.h1 = fmax3(t.A.x, t.A.y, t.A.z);
  o.h2 = fmax3(t.A.y, t.A.z, t.A.w);
  o.h3 = fmax3(t.A.z, t.A.w, t.B.x);
  o.h4 = fmax3(t.A.w, t.B.x, t.B.y);
  o.h5 = fmax3(t.B.x, t.B.y, t.B.z);
  o.h6 = fmax3(t.B.y, t.B.z, t.B.w);
  o.h7 = fmax3(t.B.z, t.B.w, t.r);
  return o;
}

// ---------- diagnostic probes ----------
// probe_a: pure coalesced float4 stream of heat.
__global__ __launch_bounds__(256) void stream_probe_a(
    const float* __restrict__ heat, u32* __restrict__ outw) {
  size_t tid = (size_t)blockIdx.x * 256 + threadIdx.x;
  size_t stride = (size_t)gridDim.x * 256;
  const float4* h4 = reinterpret_cast<const float4*>(heat);
  size_t n4 = (size_t)CHANNELS * WDIM * HDIM / 4;
  u32 c = 0;
  for (size_t i = tid; i < n4; i += stride) {
    float4 v = h4[i];
    c += (v.x > 0.5f) + (v.y > 0.5f) + (v.z > 0.5f) + (v.w > 0.5f);
  }
  for (int o = 32; o; o >>= 1) c += __shfl_down(c, o);
  if ((threadIdx.x & 63) == 0)
    outw[blockIdx.x * 4 + (threadIdx.x >> 6)] = c;
}

// probe_b: exact NMS load pattern + math, NO atomics/divergent stores.
__global__ __launch_bounds__(256) void nms_probe_b(
    const float* __restrict__ heat, u32* __restrict__ outw) {
  const int ch = blockIdx.y;
  const float* chbase = heat + (size_t)ch * (WDIM * HDIM);
  const int P = blockIdx.x * 2048 + threadIdx.x * 8;
  const int y = P >> 9, x0 = P & 511;
  R10 rt = load_row(chbase, y - 1, x0);
  R10 rm = load_row(chbase, y,     x0);
  R10 rb = load_row(chbase, y + 1, x0);
  H8 ht = hmax_row(rt), hm = hmax_row(rm), hb = hmax_row(rb);
  u32 c = 0;
  c += (rm.A.x == fmax3(ht.h0, hm.h0, hb.h0)) & (rm.A.x > 0.0f);
  c += (rm.A.y == fmax3(ht.h1, hm.h1, hb.h1)) & (rm.A.y > 0.0f);
  c += (rm.A.z == fmax3(ht.h2, hm.h2, hb.h2)) & (rm.A.z > 0.0f);
  c += (rm.A.w == fmax3(ht.h3, hm.h3, hb.h3)) & (rm.A.w > 0.0f);
  c += (rm.B.x == fmax3(ht.h4, hm.h4, hb.h4)) & (rm.B.x > 0.0f);
  c += (rm.B.y == fmax3(ht.h5, hm.h5, hb.h5)) & (rm.B.y > 0.0f);
  c += (rm.B.z == fmax3(ht.h6, hm.h6, hb.h6)) & (rm.B.z > 0.0f);
  c += (rm.B.w == fmax3(ht.h7, hm.h7, hb.h7)) & (rm.B.w > 0.0f);
  for (int o = 32; o; o >>= 1) c += __shfl_down(c, o);
  if ((threadIdx.x & 63) == 0)
    outw[(blockIdx.y * gridDim.x + blockIdx.x) * 4 + (threadIdx.x >> 6)] = c;
}

// ---------- pass 1: histogram (per-replica flush to cut cross-XCD RMW) ----------
__global__ __launch_bounds__(256) void nms_hist_kernel(
    const float* __restrict__ heat, u32* __restrict__ hist, int nrep) {
  const int ch = blockIdx.y;
  const float* chbase = heat + (size_t)ch * (WDIM * HDIM);
  __shared__ u32 lh[NBINS];
  for (int i = threadIdx.x; i < NBINS; i += 256) lh[i] = 0;
  __syncthreads();

  const int P = blockIdx.x * 2048 + threadIdx.x * 8;
  const int y = P >> 9, x0 = P & 511;
  R10 rt = load_row(chbase, y - 1, x0);
  R10 rm = load_row(chbase, y,     x0);
  R10 rb = load_row(chbase, y + 1, x0);
  H8 ht = hmax_row(rt), hm = hmax_row(rm), hb = hmax_row(rb);

#define DO_PIX(VC, HT, HM, HB)                                    \
  {                                                               \
    float v = (VC);                                               \
    if (v == fmax3((HT), (HM), (HB)) && v > 0.0f)                 \
      atomicAdd(&lh[__float_as_uint(v) >> 17], 1u);               \
  }
  DO_PIX(rm.A.x, ht.h0, hm.h0, hb.h0)
  DO_PIX(rm.A.y, ht.h1, hm.h1, hb.h1)
  DO_PIX(rm.A.z, ht.h2, hm.h2, hb.h2)
  DO_PIX(rm.A.w, ht.h3, hm.h3, hb.h3)
  DO_PIX(rm.B.x, ht.h4, hm.h4, hb.h4)
  DO_PIX(rm.B.y, ht.h5, hm.h5, hb.h5)
  DO_PIX(rm.B.z, ht.h6, hm.h6, hb.h6)
  DO_PIX(rm.B.w, ht.h7, hm.h7, hb.h7)
#undef DO_PIX

  __syncthreads();
  int rep = (blockIdx.y * gridDim.x + blockIdx.x) & (nrep - 1);
  u32* h = hist + ((size_t)rep * CHANNELS + ch) * NBINS;
  for (int i = threadIdx.x; i < NBINS; i += 256) {
    u32 c = lh[i];
    if (c) atomicAdd(&h[i], c);
  }
}

// ---------- pass 2: threshold per channel (sums replicas) ----------
__global__ __launch_bounds__(256) void thresh_kernel(
    const u32* __restrict__ hist, int nrep, int* __restrict__ thresh) {
  const int ch = blockIdx.x;
  __shared__ u32 csum[256];
  const int t = threadIdx.x;
  u32 s = 0;
  for (int r = 0; r < nrep; r++) {
    const u32* h = hist + ((size_t)r * CHANNELS + ch) * NBINS;
#pragma unroll 4
    for (int i = 0; i < NBINS / 256; i++) s += h[t * (NBINS / 256) + i];
  }
  csum[t] = s;
  __syncthreads();
  if (t == 0) {
    u32 cum = 0;
    int c;
    for (c = 255; c >= 0; c--) {
      if (cum + csum[c] >= TOPK) break;
      cum += csum[c];
    }
    int T = 0;
    if (c >= 0) {
      int b;
      for (b = c * (NBINS / 256) + (NBINS / 256) - 1; b >= c * (NBINS / 256); b--) {
        u32 bs = 0;
        for (int r = 0; r < nrep; r++)
          bs += hist[((size_t)r * CHANNELS + ch) * NBINS + b];
        cum += bs;
        if (cum >= TOPK) break;
      }
      T = b;
    }
    thresh[ch] = T;
  }
}

// ---------- pass 3: collect survivors >= thresh (LDS-buffered, 1 atomic/block) ----------
__global__ __launch_bounds__(256) void nms_collect_kernel(
    const float* __restrict__ heat, const int* __restrict__ thresh,
    float* __restrict__ cv, int* __restrict__ ci, u32* __restrict__ cnt) {
  const int ch = blockIdx.y;
  const float* chbase = heat + (size_t)ch * (WDIM * HDIM);
  __shared__ u32 lcnt, lbase;
  __shared__ float lv[2048];
  __shared__ int li[2048];
  if (threadIdx.x == 0) lcnt = 0;
  __syncthreads();

  const int T = thresh[ch];
  const int P = blockIdx.x * 2048 + threadIdx.x * 8;
  const int y = P >> 9, x0 = P & 511;
  R10 rt = load_row(chbase, y - 1, x0);
  R10 rm = load_row(chbase, y,     x0);
  R10 rb = load_row(chbase, y + 1, x0);
  H8 ht = hmax_row(rt), hm = hmax_row(rm), hb = hmax_row(rb);

#define DO_PIX(I, VC, HT, HM, HB)                                 \
  {                                                               \
    float v = (VC);                                               \
    if (v == fmax3((HT), (HM), (HB)) && v > 0.0f) {               \
      int bin = (int)(__float_as_uint(v) >> 17);                  \
      if (bin >= T) {                                             \
        u32 p = atomicAdd(&lcnt, 1u);                             \
        lv[p] = v;                                                \
        li[p] = P + (I);                                          \
      }                                                           \
    }                                                             \
  }
  DO_PIX(0, rm.A.x, ht.h0, hm.h0, hb.h0)
  DO_PIX(1, rm.A.y, ht.h1, hm.h1, hb.h1)
  DO_PIX(2, rm.A.z, ht.h2, hm.h2, hb.h2)
  DO_PIX(3, rm.A.w, ht.h3, hm.h3, hb.h3)
  DO_PIX(4, rm.B.x, ht.h4, hm.h4, hb.h4)
  DO_PIX(5, rm.B.y, ht.h5, hm.h5, hb.h5)
  DO_PIX(6, rm.B.z, ht.h6, hm.h6, hb.h6)
  DO_PIX(7, rm.B.w, ht.h7, hm.h7, hb.h7)
#undef DO_PIX

  __syncthreads();
  if (threadIdx.x == 0) lbase = atomicAdd(&cnt[ch * CNT_STRIDE], lcnt);
  __syncthreads();
  const u32 n = lcnt, base = lbase;
  for (u32 i = threadIdx.x; i < n; i += 256) {
    u32 pos = base + i;
    if (pos < CAP) {
      cv[ch * CAP + pos] = lv[i];
      ci[ch * CAP + pos] = li[i];
    }
  }
}

// key = (float_bits(v) << 32) | ~index : desc sort == (value desc, index asc)
__device__ __forceinline__ void bitonic_desc(u64* keys, int N, int nthr, int tid) {
  for (unsigned size = 2; size <= (unsigned)N; size <<= 1) {
    for (unsigned stride = size >> 1; stride > 0; stride >>= 1) {
      __syncthreads();
      for (unsigned i = tid; i < (unsigned)N; i += nthr) {
        unsigned j = i ^ stride;
        if (j > i) {
          u64 a = keys[i], b = keys[j];
          bool desc = ((i & size) == 0);
          if ((a < b) == desc) { keys[i] = b; keys[j] = a; }
        }
      }
    }
  }
  __syncthreads();
}

__global__ __launch_bounds__(1024) void select_kernel(
    const float* __restrict__ cv, const int* __restrict__ ci,
    const u32* __restrict__ cnt, float* __restrict__ s1s, int* __restrict__ s1i) {
  const int ch = blockIdx.x;
  __shared__ u64 keys[CAP];
  const int n = min((int)cnt[ch * CNT_STRIDE], CAP);
  for (int i = threadIdx.x; i < CAP; i += 1024) {
    u64 k = 0;
    if (i < n) {
      u32 vb = __float_as_uint(cv[ch * CAP + i]);
      u32 ib = ~(u32)ci[ch * CAP + i];
      k = ((u64)vb << 32) | ib;
    }
    keys[i] = k;
  }
  bitonic_desc(keys, CAP, 1024, threadIdx.x);
  for (int k = threadIdx.x; k < TOPK; k += 1024) {
    u64 key = keys[k];
    s1s[ch * TOPK + k] = __uint_as_float((u32)(key >> 32));
    s1i[ch * TOPK + k] = (int)(~(u32)key);
  }
}

__global__ __launch_bounds__(256) void batch_topk_kernel(
    const float* __restrict__ s1s, const int* __restrict__ s1i,
    float* __restrict__ out) {
  const int b = blockIdx.x;
  __shared__ u64 keys[1024];
  for (int i = threadIdx.x; i < 1024; i += 256) {
    u64 k = 0;
    if (i < 1000) {
      u32 vb = __float_as_uint(s1s[b * 1000 + i]);
      k = ((u64)vb << 32) | (u32)(~(u32)i);
    }
    keys[i] = k;
  }
  bitonic_desc(keys, 1024, 256, threadIdx.x);
  for (int k = threadIdx.x; k < TOPK; k += 256) {
    u64 key = keys[k];
    float sc = __uint_as_float((u32)(key >> 32));
    int flat = (int)(~(u32)key);
    int cls = flat / 100;
    int spatial = s1i[b * 1000 + flat];
    out[0 * 800 + b * TOPK + k] = sc;
    out[1 * 800 + b * TOPK + k] = (float)spatial;
    out[2 * 800 + b * TOPK + k] = (float)cls;
    out[3 * 800 + b * TOPK + k] = (float)(spatial >> 9);
    out[4 * 800 + b * TOPK + k] = (float)(spatial & 511);
  }
}

extern "C" void kernel_launch(void* const* d_in, const int* in_sizes, int n_in,
                              void* d_out, int out_size, void* d_ws, size_t ws_size,
                              hipStream_t stream) {
  const float* heat = (const float*)d_in[0];
  char* ws = (char*)d_ws;
  float* out = (float*)d_out;

  // 8 histogram replicas if workspace allows, else 1.
  const int nrep = (ws_size >= 25000000u) ? 8 : 1;
  size_t p = 0;
  u32* hist = (u32*)(ws + p); p += (size_t)nrep * CHANNELS * NBINS * 4;
  u32* cnt  = (u32*)(ws + p); p += (size_t)CHANNELS * CNT_STRIDE * 4;
  const size_t zero_bytes = p;  // hist + cnt
  int*   thresh = (int*)  (ws + p); p += 512;
  float* cv     = (float*)(ws + p); p += (size_t)CHANNELS * CAP * 4;
  int*   ci     = (int*)  (ws + p); p += (size_t)CHANNELS * CAP * 4;
  float* s1s    = (float*)(ws + p); p += CHANNELS * TOPK * 4;
  int*   s1i    = (int*)  (ws + p); p += CHANNELS * TOPK * 4;

  // Probes write scratch into the cv region (later guarded by cnt).
  stream_probe_a<<<2048, 256, 0, stream>>>(heat, (u32*)cv);
  dim3 nms_grid(128, CHANNELS);
  nms_probe_b<<<nms_grid, 256, 0, stream>>>(heat, (u32*)cv);

  hipMemsetAsync(d_ws, 0, zero_bytes, stream);
  nms_hist_kernel<<<nms_grid, 256, 0, stream>>>(heat, hist, nrep);
  thresh_kernel<<<CHANNELS, 256, 0, stream>>>(hist, nrep, thresh);
  nms_collect_kernel<<<nms_grid, 256, 0, stream>>>(heat, thresh, cv, ci, cnt);
  select_kernel<<<CHANNELS, 1024, 0, stream>>>(cv, ci, cnt, s1s, s1i);
  batch_topk_kernel<<<8, 256, 0, stream>>>(s1s, s1i, out);
}

// Round 4
// 263.067 us; speedup vs baseline: 5.4742x; 1.3250x over previous
//
#include <hip/hip_runtime.h>
#include <cstdint>

using u32 = unsigned int;
using u64 = unsigned long long;

#define WDIM 512
#define HDIM 512
#define CHANNELS 80   // 8 batches * 10 classes
#define SELBINS 2048
#define SORTN 4096
#define TOPK 100
#define NEG_SENTINEL -1e30f
#define CNT_STRIDE 16  // u32s per channel counter slot (64B line each)

__device__ __forceinline__ float fmax3(float a, float b, float c) {
  return fmaxf(fmaxf(a, b), c);
}

// bin: full float-bit resolution for v >= 2^-31, clamp below. Monotonic in v.
__device__ __forceinline__ int val_bin(float v) {
  int b = (int)(__float_as_uint(v) >> 17) - 6144;
  return b < 0 ? 0 : b;  // max is 8127-6144=1983 < SELBINS
}

// 10 values of one row: [l, A.x..A.w, B.x..B.w, r]
struct R10 { float l; float4 A; float4 B; float r; };
struct H8 { float h0, h1, h2, h3, h4, h5, h6, h7; };

__device__ __forceinline__ R10 load_row(const float* __restrict__ chbase, int y,
                                        int x0) {
  R10 o;
  if (y < 0 || y >= HDIM) {
    o.l = NEG_SENTINEL;
    o.A = make_float4(NEG_SENTINEL, NEG_SENTINEL, NEG_SENTINEL, NEG_SENTINEL);
    o.B = o.A;
    o.r = NEG_SENTINEL;
    return o;
  }
  const float* row = chbase + (size_t)y * WDIM;
  o.A = *reinterpret_cast<const float4*>(row + x0);
  o.B = *reinterpret_cast<const float4*>(row + x0 + 4);
  o.l = (x0 > 0) ? row[x0 - 1] : NEG_SENTINEL;
  o.r = (x0 + 8 < WDIM) ? row[x0 + 8] : NEG_SENTINEL;
  return o;
}

__device__ __forceinline__ H8 hmax_row(const R10& t) {
  H8 o;
  o.h0 = fmax3(t.l,   t.A.x, t.A.y);
  o.h1 = fmax3(t.A.x, t.A.y, t.A.z);
  o.h2 = fmax3(t.A.y, t.A.z, t.A.w);
  o.h3 = fmax3(t.A.z, t.A.w, t.B.x);
  o.h4 = fmax3(t.A.w, t.B.x, t.B.y);
  o.h5 = fmax3(t.B.x, t.B.y, t.B.z);
  o.h6 = fmax3(t.B.y, t.B.z, t.B.w);
  o.h7 = fmax3(t.B.z, t.B.w, t.r);
  return o;
}

// ---- single heat pass: compact ALL 3x3-NMS survivor indices per channel ----
__global__ __launch_bounds__(256) void nms_collect_all(
    const float* __restrict__ heat, u32* __restrict__ idx_all,
    u32* __restrict__ cnt, int cap_all) {
  const int ch = blockIdx.y;
  const float* chbase = heat + (size_t)ch * (WDIM * HDIM);
  __shared__ u32 lcnt, lbase;
  __shared__ u32 li[2048];  // block covers 2048 px; survivors <= 2048 by construction
  if (threadIdx.x == 0) lcnt = 0;
  __syncthreads();

  const int P = blockIdx.x * 2048 + threadIdx.x * 8;  // 8 px per thread, one row
  const int y = P >> 9, x0 = P & 511;
  R10 rt = load_row(chbase, y - 1, x0);
  R10 rm = load_row(chbase, y,     x0);
  R10 rb = load_row(chbase, y + 1, x0);
  H8 ht = hmax_row(rt), hm = hmax_row(rm), hb = hmax_row(rb);

#define DO_PIX(I, VC, HT, HM, HB)                                 \
  {                                                               \
    float v = (VC);                                               \
    if (v == fmax3((HT), (HM), (HB)) && v > 0.0f) {               \
      u32 p = atomicAdd(&lcnt, 1u);                               \
      li[p] = P + (I);                                            \
    }                                                             \
  }
  DO_PIX(0, rm.A.x, ht.h0, hm.h0, hb.h0)
  DO_PIX(1, rm.A.y, ht.h1, hm.h1, hb.h1)
  DO_PIX(2, rm.A.z, ht.h2, hm.h2, hb.h2)
  DO_PIX(3, rm.A.w, ht.h3, hm.h3, hb.h3)
  DO_PIX(4, rm.B.x, ht.h4, hm.h4, hb.h4)
  DO_PIX(5, rm.B.y, ht.h5, hm.h5, hb.h5)
  DO_PIX(6, rm.B.z, ht.h6, hm.h6, hb.h6)
  DO_PIX(7, rm.B.w, ht.h7, hm.h7, hb.h7)
#undef DO_PIX

  __syncthreads();
  if (threadIdx.x == 0) lbase = atomicAdd(&cnt[ch * CNT_STRIDE], lcnt);
  __syncthreads();
  const u32 n = lcnt, base = lbase;
  u32* dst = idx_all + (size_t)ch * cap_all;
  for (u32 i = threadIdx.x; i < n; i += 256) {
    u32 pos = base + i;
    if (pos < (u32)cap_all) dst[pos] = li[i];
  }
}

// key = (float_bits(v) << 32) | ~index : desc sort == (value desc, index asc)
__device__ __forceinline__ void bitonic_desc(u64* keys, int N, int nthr, int tid) {
  for (unsigned size = 2; size <= (unsigned)N; size <<= 1) {
    for (unsigned stride = size >> 1; stride > 0; stride >>= 1) {
      __syncthreads();
      for (unsigned i = tid; i < (unsigned)N; i += nthr) {
        unsigned j = i ^ stride;
        if (j > i) {
          u64 a = keys[i], b = keys[j];
          bool desc = ((i & size) == 0);
          if ((a < b) == desc) { keys[i] = b; keys[j] = a; }
        }
      }
    }
  }
  __syncthreads();
}

// ---- per-channel: hist of survivors -> threshold -> sort finalists -> top-100 ----
__global__ __launch_bounds__(1024) void select_kernel(
    const float* __restrict__ heat, const u32* __restrict__ idx_all,
    const u32* __restrict__ cnt, int cap_all,
    float* __restrict__ s1s, int* __restrict__ s1i) {
  const int ch = blockIdx.x;
  const float* chbase = heat + (size_t)ch * (WDIM * HDIM);
  const u32* idx = idx_all + (size_t)ch * cap_all;
  const int n = min((int)cnt[ch * CNT_STRIDE], cap_all);

  __shared__ u32 hist[SELBINS];
  __shared__ u64 keys[SORTN];
  __shared__ int sT;
  __shared__ u32 scand;

  for (int i = threadIdx.x; i < SELBINS; i += 1024) hist[i] = 0;
  if (threadIdx.x == 0) scand = 0;
  __syncthreads();

  // pass A: histogram of survivor values (gather from heat; L2/LLC-warm)
  for (int i = threadIdx.x; i < n; i += 1024) {
    float v = chbase[idx[i]];
    atomicAdd(&hist[val_bin(v)], 1u);
  }
  __syncthreads();

  // threshold: smallest bin T with suffix >= TOPK (serial from top, ~65 iters)
  if (threadIdx.x == 0) {
    u32 cum = 0;
    int b = SELBINS - 1;
    for (; b >= 0; b--) {
      cum += hist[b];
      if (cum >= TOPK) break;
    }
    sT = b < 0 ? 0 : b;
  }
  __syncthreads();
  const int T = sT;

  // pass B: collect finalists (bin >= T) into sort buffer
  for (int i = threadIdx.x; i < n; i += 1024) {
    u32 id = idx[i];
    float v = chbase[id];
    if (val_bin(v) >= T) {
      u32 p = atomicAdd(&scand, 1u);
      if (p < SORTN)
        keys[p] = ((u64)__float_as_uint(v) << 32) | (u32)(~id);
    }
  }
  __syncthreads();
  const int nc = min((int)scand, SORTN);
  for (int i = threadIdx.x; i < SORTN; i += 1024)
    if (i >= nc) keys[i] = 0;
  bitonic_desc(keys, SORTN, 1024, threadIdx.x);

  for (int k = threadIdx.x; k < TOPK; k += 1024) {
    u64 key = keys[k];
    s1s[ch * TOPK + k] = __uint_as_float((u32)(key >> 32));
    s1i[ch * TOPK + k] = (int)(~(u32)key);
  }
}

// ---- per-batch top-100 over the 10*100 stage-1 candidates ----
__global__ __launch_bounds__(256) void batch_topk_kernel(
    const float* __restrict__ s1s, const int* __restrict__ s1i,
    float* __restrict__ out) {
  const int b = blockIdx.x;
  __shared__ u64 keys[1024];
  for (int i = threadIdx.x; i < 1024; i += 256) {
    u64 k = 0;
    if (i < 1000) {
      u32 vb = __float_as_uint(s1s[b * 1000 + i]);
      k = ((u64)vb << 32) | (u32)(~(u32)i);
    }
    keys[i] = k;
  }
  bitonic_desc(keys, 1024, 256, threadIdx.x);
  for (int k = threadIdx.x; k < TOPK; k += 256) {
    u64 key = keys[k];
    float sc = __uint_as_float((u32)(key >> 32));
    int flat = (int)(~(u32)key);          // c*100 + j
    int cls = flat / 100;
    int spatial = s1i[b * 1000 + flat];
    out[0 * 800 + b * TOPK + k] = sc;
    out[1 * 800 + b * TOPK + k] = (float)spatial;
    out[2 * 800 + b * TOPK + k] = (float)cls;
    out[3 * 800 + b * TOPK + k] = (float)(spatial >> 9);
    out[4 * 800 + b * TOPK + k] = (float)(spatial & 511);
  }
}

extern "C" void kernel_launch(void* const* d_in, const int* in_sizes, int n_in,
                              void* d_out, int out_size, void* d_ws, size_t ws_size,
                              hipStream_t stream) {
  const float* heat = (const float*)d_in[0];
  char* ws = (char*)d_ws;
  float* out = (float*)d_out;

  // adaptive candidate capacity per channel (expected ~29.2k survivors/channel)
  int cap_all = 49152;
  {
    size_t fixed = (size_t)CHANNELS * CNT_STRIDE * 4 + 4096 + CHANNELS * TOPK * 8;
    while (cap_all > 16384 &&
           fixed + (size_t)CHANNELS * cap_all * 4 > ws_size)
      cap_all >>= 1;
  }

  size_t p = 0;
  u32* cnt     = (u32*)(ws + p); p += (size_t)CHANNELS * CNT_STRIDE * 4;
  const size_t zero_bytes = p;  // only cnt needs zeroing
  p = (p + 255) & ~(size_t)255;
  u32* idx_all = (u32*)(ws + p); p += (size_t)CHANNELS * cap_all * 4;
  float* s1s   = (float*)(ws + p); p += CHANNELS * TOPK * 4;
  int*   s1i   = (int*)  (ws + p); p += CHANNELS * TOPK * 4;

  hipMemsetAsync(d_ws, 0, zero_bytes, stream);

  dim3 nms_grid(128, CHANNELS);  // 128 blocks * 2048 px = 512*512 per channel
  nms_collect_all<<<nms_grid, 256, 0, stream>>>(heat, idx_all, cnt, cap_all);
  select_kernel<<<CHANNELS, 1024, 0, stream>>>(heat, idx_all, cnt, cap_all, s1s, s1i);
  batch_topk_kernel<<<8, 256, 0, stream>>>(s1s, s1i, out);
}

// Round 8
// 197.682 us; speedup vs baseline: 7.2849x; 1.3308x over previous
//
#include <hip/hip_runtime.h>
#include <cstdint>

using u32 = unsigned int;
using u64 = unsigned long long;

#define WDIM 512
#define HDIM 512
#define CHANNELS 80   // 8 batches * 10 classes
#define SELBINS 4096
#define SORTN 2048
#define TOPK 100
#define NEG_SENTINEL -1e30f
#define CNT_STRIDE 16  // u32s per channel counter slot (64B line each)

__device__ __forceinline__ float fmax3(float a, float b, float c) {
  return fmaxf(fmaxf(a, b), c);
}

// bin from float bits: 512 bins/octave, offset so v>=2^-8 gets bin>0.
// Monotonic in v; clamp below. Max (v<1): (126<<9)+511-60928 = 4095.
__device__ __forceinline__ int key_bin(u64 key) {
  int b = (int)((u32)(key >> 32) >> 14) - 60928;
  return b < 0 ? 0 : b;
}

struct H8 { float h0, h1, h2, h3, h4, h5, h6, h7; };
struct Row { float l; float4 A; float4 B; float r; };

// Load 8 px of row y at x0 (two float4), neighbors via wave shuffles.
// A wave (64 lanes) covers exactly one 512-px row, so lane-1/lane+1 hold
// the adjacent 8-px groups of the SAME row.
__device__ __forceinline__ Row load_row_shfl(const float* __restrict__ chbase,
                                             int y, int x0) {
  Row o;
  if (y >= 0 && y < HDIM) {
    const float* row = chbase + (size_t)y * WDIM;
    o.A = *reinterpret_cast<const float4*>(row + x0);
    o.B = *reinterpret_cast<const float4*>(row + x0 + 4);
  } else {
    o.A = make_float4(NEG_SENTINEL, NEG_SENTINEL, NEG_SENTINEL, NEG_SENTINEL);
    o.B = o.A;
  }
  o.l = __shfl_up(o.B.w, 1);
  o.r = __shfl_down(o.A.x, 1);
  int lane = threadIdx.x & 63;
  if (lane == 0) o.l = NEG_SENTINEL;    // x0 == 0
  if (lane == 63) o.r = NEG_SENTINEL;   // x0 + 8 == 512
  return o;
}

__device__ __forceinline__ H8 hmax_row(const Row& t) {
  H8 o;
  o.h0 = fmax3(t.l,   t.A.x, t.A.y);
  o.h1 = fmax3(t.A.x, t.A.y, t.A.z);
  o.h2 = fmax3(t.A.y, t.A.z, t.A.w);
  o.h3 = fmax3(t.A.z, t.A.w, t.B.x);
  o.h4 = fmax3(t.A.w, t.B.x, t.B.y);
  o.h5 = fmax3(t.B.x, t.B.y, t.B.z);
  o.h6 = fmax3(t.B.y, t.B.z, t.B.w);
  o.h7 = fmax3(t.B.z, t.B.w, t.r);
  return o;
}

// ---- single heat pass: compact ALL 3x3-NMS survivors as (value,index) keys ----
__global__ __launch_bounds__(256) void nms_collect_all(
    const float* __restrict__ heat, u64* __restrict__ keys_all,
    u32* __restrict__ cnt, int cap_all) {
  const int ch = blockIdx.y;
  const float* chbase = heat + (size_t)ch * (WDIM * HDIM);
  __shared__ u32 lcnt, lbase;
  __shared__ u64 lk[2048];  // block covers 2048 px; survivors < 2048 by construction
  if (threadIdx.x == 0) lcnt = 0;
  __syncthreads();

  const int P = blockIdx.x * 2048 + threadIdx.x * 8;  // 8 px per thread, one row
  const int y = P >> 9, x0 = P & 511;
  Row rt = load_row_shfl(chbase, y - 1, x0);
  Row rm = load_row_shfl(chbase, y,     x0);
  Row rb = load_row_shfl(chbase, y + 1, x0);
  H8 ht = hmax_row(rt), hm = hmax_row(rm), hb = hmax_row(rb);

#define DO_PIX(I, VC, HT, HM, HB)                                         \
  {                                                                       \
    float v = (VC);                                                       \
    if (v == fmax3((HT), (HM), (HB)) && v > 0.0f) {                       \
      u32 p = atomicAdd(&lcnt, 1u);                                       \
      lk[p] = ((u64)__float_as_uint(v) << 32) | (u32)(~(u32)(P + (I)));   \
    }                                                                     \
  }
  DO_PIX(0, rm.A.x, ht.h0, hm.h0, hb.h0)
  DO_PIX(1, rm.A.y, ht.h1, hm.h1, hb.h1)
  DO_PIX(2, rm.A.z, ht.h2, hm.h2, hb.h2)
  DO_PIX(3, rm.A.w, ht.h3, hm.h3, hb.h3)
  DO_PIX(4, rm.B.x, ht.h4, hm.h4, hb.h4)
  DO_PIX(5, rm.B.y, ht.h5, hm.h5, hb.h5)
  DO_PIX(6, rm.B.z, ht.h6, hm.h6, hb.h6)
  DO_PIX(7, rm.B.w, ht.h7, hm.h7, hb.h7)
#undef DO_PIX

  __syncthreads();
  if (threadIdx.x == 0) lbase = atomicAdd(&cnt[ch * CNT_STRIDE], lcnt);
  __syncthreads();
  const u32 n = lcnt, base = lbase;
  u64* dst = keys_all + (size_t)ch * cap_all;
  for (u32 i = threadIdx.x; i < n; i += 256) {
    u32 pos = base + i;
    if (pos < (u32)cap_all) dst[pos] = lk[i];
  }
}

// key = (float_bits(v) << 32) | ~index : desc sort == (value desc, index asc)
__device__ __forceinline__ void bitonic_desc(u64* keys, int N, int nthr, int tid) {
  for (unsigned size = 2; size <= (unsigned)N; size <<= 1) {
    for (unsigned stride = size >> 1; stride > 0; stride >>= 1) {
      __syncthreads();
      for (unsigned i = tid; i < (unsigned)N; i += nthr) {
        unsigned j = i ^ stride;
        if (j > i) {
          u64 a = keys[i], b = keys[j];
          bool desc = ((i & size) == 0);
          if ((a < b) == desc) { keys[i] = b; keys[j] = a; }
        }
      }
    }
  }
  __syncthreads();
}

// ---- per-channel: hist(keys) -> threshold bin -> sort finalists -> top-100 ----
__global__ __launch_bounds__(1024) void select_kernel(
    const u64* __restrict__ keys_all, const u32* __restrict__ cnt, int cap_all,
    float* __restrict__ s1s, int* __restrict__ s1i) {
  const int ch = blockIdx.x;
  const u64* keys = keys_all + (size_t)ch * cap_all;
  const int n = min((int)cnt[ch * CNT_STRIDE], cap_all);

  __shared__ u32 hist[SELBINS];
  __shared__ u64 sk[SORTN];
  __shared__ int sT;
  __shared__ u32 scand;

  for (int i = threadIdx.x; i < SELBINS; i += 1024) hist[i] = 0;
  if (threadIdx.x == 0) scand = 0;
  __syncthreads();

  // pass A: histogram (linear read of packed keys)
  for (int i = threadIdx.x; i < n; i += 1024)
    atomicAdd(&hist[key_bin(keys[i])], 1u);
  __syncthreads();

  // threshold: smallest bin T with suffix >= TOPK (expected ~1-2 iters)
  if (threadIdx.x == 0) {
    u32 cum = 0;
    int b = SELBINS - 1;
    for (; b >= 0; b--) {
      cum += hist[b];
      if (cum >= TOPK) break;
    }
    sT = b < 0 ? 0 : b;
  }
  __syncthreads();
  const int T = sT;

  // pass B: collect finalists (bin >= T)
  for (int i = threadIdx.x; i < n; i += 1024) {
    u64 k = keys[i];
    if (key_bin(k) >= T) {
      u32 p = atomicAdd(&scand, 1u);
      if (p < SORTN) sk[p] = k;
    }
  }
  __syncthreads();
  const int nc = min((int)scand, SORTN);
  for (int i = threadIdx.x; i < SORTN; i += 1024)
    if (i >= nc) sk[i] = 0;
  bitonic_desc(sk, SORTN, 1024, threadIdx.x);

  for (int k = threadIdx.x; k < TOPK; k += 1024) {
    u64 key = sk[k];
    s1s[ch * TOPK + k] = __uint_as_float((u32)(key >> 32));
    s1i[ch * TOPK + k] = (int)(~(u32)key);
  }
}

// ---- per-batch top-100 over the 10*100 stage-1 candidates ----
__global__ __launch_bounds__(256) void batch_topk_kernel(
    const float* __restrict__ s1s, const int* __restrict__ s1i,
    float* __restrict__ out) {
  const int b = blockIdx.x;
  __shared__ u64 keys[1024];
  for (int i = threadIdx.x; i < 1024; i += 256) {
    u64 k = 0;
    if (i < 1000) {
      u32 vb = __float_as_uint(s1s[b * 1000 + i]);
      k = ((u64)vb << 32) | (u32)(~(u32)i);
    }
    keys[i] = k;
  }
  bitonic_desc(keys, 1024, 256, threadIdx.x);
  for (int k = threadIdx.x; k < TOPK; k += 256) {
    u64 key = keys[k];
    float sc = __uint_as_float((u32)(key >> 32));
    int flat = (int)(~(u32)key);          // c*100 + j
    int cls = flat / 100;
    int spatial = s1i[b * 1000 + flat];
    out[0 * 800 + b * TOPK + k] = sc;
    out[1 * 800 + b * TOPK + k] = (float)spatial;
    out[2 * 800 + b * TOPK + k] = (float)cls;
    out[3 * 800 + b * TOPK + k] = (float)(spatial >> 9);
    out[4 * 800 + b * TOPK + k] = (float)(spatial & 511);
  }
}

extern "C" void kernel_launch(void* const* d_in, const int* in_sizes, int n_in,
                              void* d_out, int out_size, void* d_ws, size_t ws_size,
                              hipStream_t stream) {
  const float* heat = (const float*)d_in[0];
  char* ws = (char*)d_ws;
  float* out = (float*)d_out;

  // per-channel key capacity (expected ~29.3k survivors/channel, sd ~160)
  int cap_all = 49152;
  {
    size_t fixed = (size_t)CHANNELS * CNT_STRIDE * 4 + 4096 + CHANNELS * TOPK * 8;
    while (cap_all > 16384 &&
           fixed + (size_t)CHANNELS * cap_all * 8 > ws_size)
      cap_all >>= 1;
  }

  size_t p = 0;
  u32* cnt      = (u32*)(ws + p); p += (size_t)CHANNELS * CNT_STRIDE * 4;
  const size_t zero_bytes = p;  // only cnt needs zeroing
  p = (p + 255) & ~(size_t)255;
  u64* keys_all = (u64*)(ws + p); p += (size_t)CHANNELS * cap_all * 8;
  float* s1s    = (float*)(ws + p); p += CHANNELS * TOPK * 4;
  int*   s1i    = (int*)  (ws + p); p += CHANNELS * TOPK * 4;

  hipMemsetAsync(d_ws, 0, zero_bytes, stream);

  dim3 nms_grid(128, CHANNELS);  // 128 blocks * 2048 px = 512*512 per channel
  nms_collect_all<<<nms_grid, 256, 0, stream>>>(heat, keys_all, cnt, cap_all);
  select_kernel<<<CHANNELS, 1024, 0, stream>>>(keys_all, cnt, cap_all, s1s, s1i);
  batch_topk_kernel<<<8, 256, 0, stream>>>(s1s, s1i, out);
}

// Round 9
// 188.443 us; speedup vs baseline: 7.6420x; 1.0490x over previous
//
#include <hip/hip_runtime.h>
#include <cstdint>

using u32 = unsigned int;
using u64 = unsigned long long;

#define WDIM 512
#define HDIM 512
#define CHANNELS 80   // 8 batches * 10 classes
#define NSTRIP 8      // row-strips per channel (64 rows each)
#define STRIPROWS 64
#define KEYCAP 4096   // per-strip survivor cap (expected ~3.7k, sd ~60)
#define HBINS 4096
#define SORTA 512     // per-strip finalist sort size
#define TOPK 100
#define NEG_SENTINEL -1e30f

__device__ __forceinline__ float fmax3(float a, float b, float c) {
  return fmaxf(fmaxf(a, b), c);
}

// bin from float bits: 512 bins/octave, offset so v>=2^-8 maps above 0.
// Monotonic in v; clamp below. Max (v<1.0): (1065353215>>14)-60928 = 4095.
__device__ __forceinline__ int key_bin(u64 key) {
  int b = (int)((u32)(key >> 32) >> 14) - 60928;
  return b < 0 ? 0 : b;
}

struct H8 { float h0, h1, h2, h3, h4, h5, h6, h7; };
struct Row { float l; float4 A; float4 B; float r; };

// Load 8 px of row y at x0 = lane*8 (two float4); horizontal neighbors via
// wave shuffles (one wave = one full 512-px row).
__device__ __forceinline__ Row load_row_shfl(const float* __restrict__ chbase,
                                             int y, int x0) {
  Row o;
  if (y >= 0 && y < HDIM) {
    const float* row = chbase + (size_t)y * WDIM;
    o.A = *reinterpret_cast<const float4*>(row + x0);
    o.B = *reinterpret_cast<const float4*>(row + x0 + 4);
  } else {
    o.A = make_float4(NEG_SENTINEL, NEG_SENTINEL, NEG_SENTINEL, NEG_SENTINEL);
    o.B = o.A;
  }
  o.l = __shfl_up(o.B.w, 1);
  o.r = __shfl_down(o.A.x, 1);
  int lane = threadIdx.x & 63;
  if (lane == 0) o.l = NEG_SENTINEL;    // x == 0 edge
  if (lane == 63) o.r = NEG_SENTINEL;   // x == 511 edge
  return o;
}

__device__ __forceinline__ H8 hmax_row(const Row& t) {
  H8 o;
  o.h0 = fmax3(t.l,   t.A.x, t.A.y);
  o.h1 = fmax3(t.A.x, t.A.y, t.A.z);
  o.h2 = fmax3(t.A.y, t.A.z, t.A.w);
  o.h3 = fmax3(t.A.z, t.A.w, t.B.x);
  o.h4 = fmax3(t.A.w, t.B.x, t.B.y);
  o.h5 = fmax3(t.B.x, t.B.y, t.B.z);
  o.h6 = fmax3(t.B.y, t.B.z, t.B.w);
  o.h7 = fmax3(t.B.z, t.B.w, t.r);
  return o;
}

// key = (float_bits(v) << 32) | ~index : desc sort == (value desc, index asc)
__device__ __forceinline__ void bitonic_desc(u64* keys, int N, int nthr, int tid) {
  for (unsigned size = 2; size <= (unsigned)N; size <<= 1) {
    for (unsigned stride = size >> 1; stride > 0; stride >>= 1) {
      __syncthreads();
      for (unsigned i = tid; i < (unsigned)N; i += nthr) {
        unsigned j = i ^ stride;
        if (j > i) {
          u64 a = keys[i], b = keys[j];
          bool desc = ((i & size) == 0);
          if ((a < b) == desc) { keys[i] = b; keys[j] = a; }
        }
      }
    }
  }
  __syncthreads();
}

// ---- fused: 3x3 NMS + per-strip exact top-100 (one heat read, no globals) ----
// grid = (NSTRIP, CHANNELS), 512 threads (8 waves; wave w rolls rows w*8..w*8+7)
__global__ __launch_bounds__(512) void nms_topk_strip(
    const float* __restrict__ heat, u64* __restrict__ s1p) {
  const int strip = blockIdx.x, ch = blockIdx.y;
  const float* chbase = heat + (size_t)ch * (WDIM * HDIM);

  __shared__ u64 keys[KEYCAP];
  __shared__ u32 hist[HBINS];
  __shared__ u64 sk[SORTA];
  __shared__ u32 lcnt, scand;
  __shared__ int sT;

  for (int i = threadIdx.x; i < HBINS; i += 512) hist[i] = 0;
  if (threadIdx.x == 0) { lcnt = 0; scand = 0; }
  __syncthreads();

  const int lane = threadIdx.x & 63;
  const int wave = threadIdx.x >> 6;
  const int x0 = lane * 8;
  const int yb = strip * STRIPROWS + wave * 8;

  Row rm = load_row_shfl(chbase, yb, x0);
  H8 ht = hmax_row(load_row_shfl(chbase, yb - 1, x0));
  H8 hm = hmax_row(rm);

  for (int j = 0; j < 8; j++) {
    const int y = yb + j;
    Row rb = load_row_shfl(chbase, y + 1, x0);
    H8 hb = hmax_row(rb);
    const int P = (y << 9) + x0;

#define DO_PIX(I, VC, HX)                                                  \
    {                                                                      \
      float v = (VC);                                                      \
      if (v == fmax3(ht.HX, hm.HX, hb.HX) && v > 0.0f) {                   \
        u32 p = atomicAdd(&lcnt, 1u);                                      \
        if (p < KEYCAP)                                                    \
          keys[p] = ((u64)__float_as_uint(v) << 32) | (u32)(~(u32)(P + (I))); \
      }                                                                    \
    }
    DO_PIX(0, rm.A.x, h0)
    DO_PIX(1, rm.A.y, h1)
    DO_PIX(2, rm.A.z, h2)
    DO_PIX(3, rm.A.w, h3)
    DO_PIX(4, rm.B.x, h4)
    DO_PIX(5, rm.B.y, h5)
    DO_PIX(6, rm.B.z, h6)
    DO_PIX(7, rm.B.w, h7)
#undef DO_PIX

    rm = rb; ht = hm; hm = hb;
  }

  __syncthreads();
  const int n = min((int)lcnt, KEYCAP);

  // histogram of strip survivors
  for (int i = threadIdx.x; i < n; i += 512)
    atomicAdd(&hist[key_bin(keys[i])], 1u);
  __syncthreads();

  // smallest bin T with suffix count >= TOPK (few iterations: top bins dense)
  if (threadIdx.x == 0) {
    u32 cum = 0;
    int b = HBINS - 1;
    for (; b >= 0; b--) {
      cum += hist[b];
      if (cum >= TOPK) break;
    }
    sT = b < 0 ? 0 : b;
  }
  __syncthreads();
  const int T = sT;

  // compact finalists
  for (int i = threadIdx.x; i < n; i += 512) {
    u64 k = keys[i];
    if (key_bin(k) >= T) {
      u32 p = atomicAdd(&scand, 1u);
      if (p < SORTA) sk[p] = k;
    }
  }
  __syncthreads();
  const int nc = min((int)scand, SORTA);
  for (int i = threadIdx.x; i < SORTA; i += 512)
    if (i >= nc) sk[i] = 0;
  bitonic_desc(sk, SORTA, 512, threadIdx.x);

  u64* dst = s1p + ((size_t)ch * NSTRIP + strip) * TOPK;
  for (int k = threadIdx.x; k < TOPK; k += 512) dst[k] = sk[k];
}

// ---- per-channel merge: 8*100 strip keys -> channel top-100 keys ----
__global__ __launch_bounds__(256) void merge_channel(
    const u64* __restrict__ s1p, u64* __restrict__ chtop) {
  const int ch = blockIdx.x;
  __shared__ u64 sk[1024];
  const u64* src = s1p + (size_t)ch * NSTRIP * TOPK;
  for (int i = threadIdx.x; i < 1024; i += 256)
    sk[i] = (i < NSTRIP * TOPK) ? src[i] : 0;
  bitonic_desc(sk, 1024, 256, threadIdx.x);
  for (int k = threadIdx.x; k < TOPK; k += 256)
    chtop[(size_t)ch * TOPK + k] = sk[k];
}

// ---- per-batch top-100 over the 10*100 channel candidates ----
__global__ __launch_bounds__(256) void batch_topk_kernel(
    const u64* __restrict__ chtop, float* __restrict__ out) {
  const int b = blockIdx.x;
  __shared__ u64 sk[1024];
  const u64* base = chtop + (size_t)b * 10 * TOPK;
  for (int i = threadIdx.x; i < 1024; i += 256) {
    u64 k = 0;
    if (i < 1000) {
      u32 vb = (u32)(base[i] >> 32);
      k = ((u64)vb << 32) | (u32)(~(u32)i);  // tie-break: lower flat idx first
    }
    sk[i] = k;
  }
  bitonic_desc(sk, 1024, 256, threadIdx.x);
  for (int k = threadIdx.x; k < TOPK; k += 256) {
    u64 key = sk[k];
    float sc = __uint_as_float((u32)(key >> 32));
    int flat = (int)(~(u32)key);                     // c*100 + j
    int cls = flat / 100;
    int spatial = (int)(~(u32)(base[flat]));         // low 32 = ~spatial
    out[0 * 800 + b * TOPK + k] = sc;
    out[1 * 800 + b * TOPK + k] = (float)spatial;
    out[2 * 800 + b * TOPK + k] = (float)cls;
    out[3 * 800 + b * TOPK + k] = (float)(spatial >> 9);   // y
    out[4 * 800 + b * TOPK + k] = (float)(spatial & 511);  // x
  }
}

extern "C" void kernel_launch(void* const* d_in, const int* in_sizes, int n_in,
                              void* d_out, int out_size, void* d_ws, size_t ws_size,
                              hipStream_t stream) {
  const float* heat = (const float*)d_in[0];
  char* ws = (char*)d_ws;
  float* out = (float*)d_out;

  size_t p = 0;
  u64* s1p   = (u64*)(ws + p); p += (size_t)CHANNELS * NSTRIP * TOPK * 8;  // 512 KB
  u64* chtop = (u64*)(ws + p); p += (size_t)CHANNELS * TOPK * 8;           // 64 KB

  dim3 gridA(NSTRIP, CHANNELS);  // 640 blocks
  nms_topk_strip<<<gridA, 512, 0, stream>>>(heat, s1p);
  merge_channel<<<CHANNELS, 256, 0, stream>>>(s1p, chtop);
  batch_topk_kernel<<<8, 256, 0, stream>>>(chtop, out);
}